// Round 1
// baseline (409.501 us; speedup 1.0000x reference)
//
#include <hip/hip_runtime.h>
#include <hip/hip_bf16.h>
#include <math.h>

// Problem constants (from reference setup_inputs)
constexpr int B     = 64;      // batch
constexpr int C     = 512;     // query input dim
constexpr int D     = 128;     // key/value dim
constexpr int NKEYS = 200000;  // memory size
constexpr int K     = 8;       // top_k

// kernel-2 decomposition
constexpr int NBLK2 = 512;                           // blocks
constexpr int WPB   = 4;                             // waves per block
constexpr int TOTW  = NBLK2 * WPB;                   // 2048 waves
constexpr int PERW  = (NKEYS + TOTW - 1) / TOTW;     // 98 keys per wave

// ---------------------------------------------------------------------------
// top-8 register insertion (static indices after unroll)
__device__ __forceinline__ void topk_insert(float (&tv)[K], int (&ti)[K], float s, int n) {
    if (s <= tv[K - 1]) return;
    tv[K - 1] = s; ti[K - 1] = n;
#pragma unroll
    for (int j = K - 1; j > 0; --j) {
        if (tv[j] > tv[j - 1]) {
            float t = tv[j]; tv[j] = tv[j - 1]; tv[j - 1] = t;
            int   u = ti[j]; ti[j] = ti[j - 1]; ti[j - 1] = u;
        }
    }
}

// ---------------------------------------------------------------------------
// Kernel 1: q = query @ Wq + bq ; qn = l2norm(q) ; store transposed qt[d][b]
__global__ __launch_bounds__(128)
void k1_qproj(const float* __restrict__ query, const float* __restrict__ Wq,
              const float* __restrict__ bq, float* __restrict__ qt) {
    const int b = blockIdx.x;
    const int d = threadIdx.x;
    float acc = bq[d];
    const float* qr = query + (size_t)b * C;  // wave-uniform row
#pragma unroll 4
    for (int c = 0; c < C; ++c) acc = fmaf(qr[c], Wq[(size_t)c * D + d], acc);
    float ss = acc * acc;
#pragma unroll
    for (int off = 32; off > 0; off >>= 1) ss += __shfl_xor(ss, off);
    __shared__ float w[2];
    if ((d & 63) == 0) w[d >> 6] = ss;
    __syncthreads();
    const float tot = w[0] + w[1];
    const float inv = 1.0f / fmaxf(sqrtf(tot), 1e-12f);
    qt[(size_t)d * B + b] = acc * inv;
}

// ---------------------------------------------------------------------------
// Kernel 2: sim = (qn . k) * invnorm(k) * imp ; fused per-wave top-8
// lane = batch (q row in 128 VGPRs); keys via wave-uniform scalar loads.
__global__ __launch_bounds__(256)
void k2_sim_topk(const float* __restrict__ keys, const float* __restrict__ imp,
                 const float* __restrict__ qt,
                 float* __restrict__ cval, int* __restrict__ cidx) {
    const int lane = threadIdx.x & 63;
    // force wave index into SGPR so key pointers are provably wave-uniform
    const int wv   = __builtin_amdgcn_readfirstlane(threadIdx.x >> 6);
    const int wid  = blockIdx.x * WPB + wv;
    const int kbeg = wid * PERW;
    const int kend = min(kbeg + PERW, NKEYS);

    __shared__ float invn[WPB][PERW + 6];
    __shared__ float mval[WPB][B][K + 1];
    __shared__ int   midx[WPB][B][K + 1];

    // ---- phase 1: key norms (coalesced float4, 2 keys per wave-iteration) ----
    const int half = lane >> 5, l32 = lane & 31;
    for (int base = kbeg; base < kend; base += 2) {
        const int n = base + half;
        float ss = 0.0f;
        if (n < kend) {
            const float4 v = reinterpret_cast<const float4*>(keys + (size_t)n * D)[l32];
            ss = v.x * v.x + v.y * v.y + v.z * v.z + v.w * v.w;
        }
#pragma unroll
        for (int off = 16; off > 0; off >>= 1) ss += __shfl_xor(ss, off);
        if (l32 == 0 && n < kend)
            invn[wv][n - kbeg] = 1.0f / fmaxf(sqrtf(ss), 1e-12f);
    }

    // ---- load my batch's normalized q row into registers (coalesced) ----
    float q[D];
#pragma unroll
    for (int d = 0; d < D; ++d) q[d] = qt[(size_t)d * B + lane];

    // ---- phase 2: dots, 4 keys in flight, running top-8 ----
    float tv[K]; int ti[K];
#pragma unroll
    for (int j = 0; j < K; ++j) { tv[j] = -INFINITY; ti[j] = 0; }

    for (int n0 = kbeg; n0 < kend; n0 += 4) {
        const int n1 = min(n0 + 1, NKEYS - 1);
        const int n2 = min(n0 + 2, NKEYS - 1);
        const int n3 = min(n0 + 3, NKEYS - 1);
        const float* __restrict__ k0 = keys + (size_t)n0 * D;
        const float* __restrict__ k1 = keys + (size_t)n1 * D;
        const float* __restrict__ k2 = keys + (size_t)n2 * D;
        const float* __restrict__ k3 = keys + (size_t)n3 * D;
        float a0 = 0.f, a1 = 0.f, a2 = 0.f, a3 = 0.f;
#pragma unroll
        for (int d = 0; d < D; ++d) {
            const float qd = q[d];
            a0 = fmaf(qd, k0[d], a0);
            a1 = fmaf(qd, k1[d], a1);
            a2 = fmaf(qd, k2[d], a2);
            a3 = fmaf(qd, k3[d], a3);
        }
        const float s0 = a0 * invn[wv][n0 - kbeg] * imp[n0];
        const float s1 = a1 * invn[wv][n1 - kbeg] * imp[n1];
        const float s2 = a2 * invn[wv][n2 - kbeg] * imp[n2];
        const float s3 = a3 * invn[wv][n3 - kbeg] * imp[n3];
        topk_insert(tv, ti, s0, n0);
        if (n0 + 1 < kend) topk_insert(tv, ti, s1, n0 + 1);
        if (n0 + 2 < kend) topk_insert(tv, ti, s2, n0 + 2);
        if (n0 + 3 < kend) topk_insert(tv, ti, s3, n0 + 3);
    }

    // ---- per-block merge: 4 waves x 8 -> 8 per batch ----
#pragma unroll
    for (int j = 0; j < K; ++j) { mval[wv][lane][j] = tv[j]; midx[wv][lane][j] = ti[j]; }
    __syncthreads();
    if (wv == 0) {
        for (int r = 0; r < K; ++r) {
            float best = -INFINITY; int bw = 0, bj = 0;
            for (int w = 0; w < WPB; ++w)
#pragma unroll
                for (int j = 0; j < K; ++j) {
                    const float v = mval[w][lane][j];
                    if (v > best) { best = v; bw = w; bj = j; }
                }
            cval[((size_t)blockIdx.x * B + lane) * K + r] = best;
            cidx[((size_t)blockIdx.x * B + lane) * K + r] = midx[bw][lane][bj];
            mval[bw][lane][bj] = -INFINITY;
        }
    }
}

// ---------------------------------------------------------------------------
// Kernel 3: merge 512 blocks' candidates -> global top-8 per batch
__global__ __launch_bounds__(64)
void k3_merge(const float* __restrict__ cval, const int* __restrict__ cidx,
              int* __restrict__ topidx) {
    const int b    = blockIdx.x;
    const int lane = threadIdx.x;  // 0..63
    constexpr int NC = NBLK2 * K;  // 4096 candidates per batch

    __shared__ float sv[64 * (K + 1)];
    __shared__ int   si[64 * (K + 1)];

    float tv[K]; int ti[K];
#pragma unroll
    for (int j = 0; j < K; ++j) { tv[j] = -INFINITY; ti[j] = 0; }

    for (int i = 0; i < NC / 64; ++i) {
        const int e   = lane + 64 * i;
        const int blk = e >> 3, j = e & 7;
        const size_t a = ((size_t)blk * B + b) * K + j;
        const float v = cval[a];
        if (v > tv[K - 1]) topk_insert(tv, ti, v, cidx[a]);
    }
#pragma unroll
    for (int j = 0; j < K; ++j) {
        sv[lane * (K + 1) + j] = tv[j];
        si[lane * (K + 1) + j] = ti[j];
    }
    __syncthreads();

    for (int r = 0; r < K; ++r) {
        float best = -INFINITY; int bp = lane * (K + 1);
#pragma unroll
        for (int j = 0; j < K; ++j) {
            const float v = sv[lane * (K + 1) + j];
            if (v > best) { best = v; bp = lane * (K + 1) + j; }
        }
#pragma unroll
        for (int off = 32; off > 0; off >>= 1) {
            const float ov = __shfl_xor(best, off);
            const int   op = __shfl_xor(bp, off);
            if (ov > best || (ov == best && op < bp)) { best = ov; bp = op; }
        }
        if (lane == 0) {
            topidx[b * K + r] = si[bp];
            sv[bp] = -INFINITY;
        }
        __syncthreads();
    }
}

// ---------------------------------------------------------------------------
// Kernel 4: gather values, softmax attention, output projection
__global__ __launch_bounds__(128)
void k4_attend(const float* __restrict__ values, const int* __restrict__ topidx,
               const float* __restrict__ Wa, const float* __restrict__ ba,
               const float* __restrict__ Wc, const float* __restrict__ bc,
               float* __restrict__ out) {
    const int b = blockIdx.x;
    const int d = threadIdx.x;  // 0..127

    __shared__ float part[2][K];
    __shared__ float scores[K];
    __shared__ float comb[D];

    int idx[K];
#pragma unroll
    for (int k = 0; k < K; ++k) idx[k] = topidx[b * K + k];
    float v[K];
#pragma unroll
    for (int k = 0; k < K; ++k) v[k] = values[(size_t)idx[k] * D + d];

    const float wa = Wa[d];
    const int wvv = d >> 6;
#pragma unroll
    for (int k = 0; k < K; ++k) {
        float p = v[k] * wa;
#pragma unroll
        for (int off = 32; off > 0; off >>= 1) p += __shfl_xor(p, off);
        if ((d & 63) == 0) part[wvv][k] = p;
    }
    __syncthreads();
    if (d == 0) {
        float lg[K]; float mx = -INFINITY;
#pragma unroll
        for (int k = 0; k < K; ++k) { lg[k] = part[0][k] + part[1][k] + ba[0]; mx = fmaxf(mx, lg[k]); }
        float sum = 0.0f;
#pragma unroll
        for (int k = 0; k < K; ++k) { lg[k] = expf(lg[k] - mx); sum += lg[k]; }
        const float rs = 1.0f / sum;
#pragma unroll
        for (int k = 0; k < K; ++k) scores[k] = lg[k] * rs;
    }
    __syncthreads();

    float c = 0.0f;
#pragma unroll
    for (int k = 0; k < K; ++k) c = fmaf(scores[k], v[k], c);
    comb[d] = c;
    __syncthreads();

    float acc = bc[d];
    for (int dd = 0; dd < D; ++dd) acc = fmaf(comb[dd], Wc[(size_t)dd * D + d], acc);
    out[(size_t)b * D + d] = acc;
}

// ---------------------------------------------------------------------------
extern "C" void kernel_launch(void* const* d_in, const int* in_sizes, int n_in,
                              void* d_out, int out_size, void* d_ws, size_t ws_size,
                              hipStream_t stream) {
    const float* query = (const float*)d_in[0];   // [64,512]
    const float* keys  = (const float*)d_in[1];   // [200000,128]
    const float* vals  = (const float*)d_in[2];   // [200000,128]
    const float* imp   = (const float*)d_in[3];   // [200000]
    const float* Wq    = (const float*)d_in[4];   // [512,128]
    const float* bq    = (const float*)d_in[5];   // [128]
    const float* Wa    = (const float*)d_in[6];   // [128]
    const float* ba    = (const float*)d_in[7];   // [1]
    const float* Wc    = (const float*)d_in[8];   // [128,128]
    const float* bc    = (const float*)d_in[9];   // [128]
    // d_in[10] = top_k (always 8 per setup)

    float* out = (float*)d_out;

    // workspace layout (floats): ~2.1 MB
    float* qt     = (float*)d_ws;                 // 128*64
    float* cval   = qt + (size_t)D * B;           // 512*64*8
    int*   cidx   = (int*)(cval + (size_t)NBLK2 * B * K);
    int*   topidx = cidx + (size_t)NBLK2 * B * K; // 64*8

    k1_qproj<<<B, D, 0, stream>>>(query, Wq, bq, qt);
    k2_sim_topk<<<NBLK2, 256, 0, stream>>>(keys, imp, qt, cval, cidx);
    k3_merge<<<B, 64, 0, stream>>>(cval, cidx, topidx);
    k4_attend<<<B, D, 0, stream>>>(vals, topidx, Wa, ba, Wc, bc, out);
}

// Round 2
// 384.774 us; speedup vs baseline: 1.0643x; 1.0643x over previous
//
#include <hip/hip_runtime.h>
#include <hip/hip_bf16.h>
#include <math.h>

// Problem constants (from reference setup_inputs)
constexpr int B     = 64;      // batch
constexpr int C     = 512;     // query input dim
constexpr int D     = 128;     // key/value dim
constexpr int NKEYS = 200000;  // memory size
constexpr int K     = 8;       // top_k

// kernel-2 decomposition
constexpr int NBLK2 = 512;                           // blocks
constexpr int WPB   = 4;                             // waves per block
constexpr int TOTW  = NBLK2 * WPB;                   // 2048 waves
constexpr int PERW  = (NKEYS + TOTW - 1) / TOTW;     // 98 keys per wave

// ---------------------------------------------------------------------------
// top-8 register insertion (static indices after unroll)
__device__ __forceinline__ void topk_insert(float (&tv)[K], int (&ti)[K], float s, int n) {
    if (s <= tv[K - 1]) return;
    tv[K - 1] = s; ti[K - 1] = n;
#pragma unroll
    for (int j = K - 1; j > 0; --j) {
        if (tv[j] > tv[j - 1]) {
            float t = tv[j]; tv[j] = tv[j - 1]; tv[j - 1] = t;
            int   u = ti[j]; ti[j] = ti[j - 1]; ti[j - 1] = u;
        }
    }
}

// ---------------------------------------------------------------------------
// Kernel 1: q = query @ Wq + bq ; qn = l2norm(q) ; store transposed qt[d][b]
// 256 threads: thread (d, h) accumulates half of C, combine via LDS.
__global__ __launch_bounds__(256)
void k1_qproj(const float* __restrict__ query, const float* __restrict__ Wq,
              const float* __restrict__ bq, float* __restrict__ qt) {
    const int b = blockIdx.x;
    const int t = threadIdx.x;
    const int d = t & 127;
    const int h = t >> 7;                       // 0 or 1: which half of C
    const float* qr = query + (size_t)b * C;    // wave-uniform row

    float acc = 0.0f;
    const int c0 = h * (C / 2);
#pragma unroll 8
    for (int c = 0; c < C / 2; ++c)
        acc = fmaf(qr[c0 + c], Wq[(size_t)(c0 + c) * D + d], acc);

    __shared__ float part[2][D];
    part[h][d] = acc;
    __syncthreads();
    if (h == 0) {
        const float a = part[0][d] + part[1][d] + bq[d];
        float ss = a * a;
#pragma unroll
        for (int off = 32; off > 0; off >>= 1) ss += __shfl_xor(ss, off);
        __shared__ float w[2];
        if ((d & 63) == 0) w[d >> 6] = ss;
        __syncthreads();
        const float inv = 1.0f / fmaxf(sqrtf(w[0] + w[1]), 1e-12f);
        qt[(size_t)d * B + b] = a * inv;
    }
}

// ---------------------------------------------------------------------------
// Kernel 2: sim = (qn . k) * invnorm(k) * imp ; fused per-wave top-8
// lane = batch. q row lives in 128 VGPRs -- ALL indexing is compile-time
// static (full unroll) so the array cannot be demoted to scratch.
__global__ __launch_bounds__(256, 2)
void k2_sim_topk(const float* __restrict__ keys, const float* __restrict__ imp,
                 const float* __restrict__ qt,
                 float* __restrict__ cval, int* __restrict__ cidx) {
    const int lane = threadIdx.x & 63;
    const int wv   = __builtin_amdgcn_readfirstlane(threadIdx.x >> 6);
    const int wid  = blockIdx.x * WPB + wv;
    const int kbeg = wid * PERW;
    const int kend = min(kbeg + PERW, NKEYS);

    __shared__ float invn[WPB][PERW + 6];
    __shared__ float mval[WPB][B][K + 1];
    __shared__ int   midx[WPB][B][K + 1];

    // ---- phase 1: key inverse norms (coalesced float4; unroll 4 for MLP) ----
    const int half = lane >> 5, l32 = lane & 31;
#pragma unroll 4
    for (int base = kbeg; base < kend; base += 2) {
        const int n = base + half;
        float ss = 0.0f;
        if (n < kend) {
            const float4 v = reinterpret_cast<const float4*>(keys + (size_t)n * D)[l32];
            ss = v.x * v.x + v.y * v.y + v.z * v.z + v.w * v.w;
        }
#pragma unroll
        for (int off = 16; off > 0; off >>= 1) ss += __shfl_xor(ss, off);
        if (l32 == 0 && n < kend)
            invn[wv][n - kbeg] = 1.0f / fmaxf(sqrtf(ss), 1e-12f);
    }

    // ---- my batch's normalized q row -> registers (static indices) ----
    float q[D];
#pragma unroll
    for (int d = 0; d < D; ++d) q[d] = qt[(size_t)d * B + lane];

    // ---- phase 2: dots, 4 keys in flight, running top-8 ----
    float tv[K]; int ti[K];
#pragma unroll
    for (int j = 0; j < K; ++j) { tv[j] = -INFINITY; ti[j] = 0; }

    for (int n0 = kbeg; n0 < kend; n0 += 4) {
        const int n1 = min(n0 + 1, NKEYS - 1);
        const int n2 = min(n0 + 2, NKEYS - 1);
        const int n3 = min(n0 + 3, NKEYS - 1);
        const float4* __restrict__ kp0 = reinterpret_cast<const float4*>(keys + (size_t)n0 * D);
        const float4* __restrict__ kp1 = reinterpret_cast<const float4*>(keys + (size_t)n1 * D);
        const float4* __restrict__ kp2 = reinterpret_cast<const float4*>(keys + (size_t)n2 * D);
        const float4* __restrict__ kp3 = reinterpret_cast<const float4*>(keys + (size_t)n3 * D);
        float a0 = 0.f, a1 = 0.f, a2 = 0.f, a3 = 0.f;
#pragma unroll
        for (int c = 0; c < D / 4; ++c) {          // FULL unroll: q[] static
            const float4 v0 = kp0[c];
            const float4 v1 = kp1[c];
            const float4 v2 = kp2[c];
            const float4 v3 = kp3[c];
            a0 = fmaf(q[4*c], v0.x, fmaf(q[4*c+1], v0.y, fmaf(q[4*c+2], v0.z, fmaf(q[4*c+3], v0.w, a0))));
            a1 = fmaf(q[4*c], v1.x, fmaf(q[4*c+1], v1.y, fmaf(q[4*c+2], v1.z, fmaf(q[4*c+3], v1.w, a1))));
            a2 = fmaf(q[4*c], v2.x, fmaf(q[4*c+1], v2.y, fmaf(q[4*c+2], v2.z, fmaf(q[4*c+3], v2.w, a2))));
            a3 = fmaf(q[4*c], v3.x, fmaf(q[4*c+1], v3.y, fmaf(q[4*c+2], v3.z, fmaf(q[4*c+3], v3.w, a3))));
        }
        const float s0 = a0 * invn[wv][n0 - kbeg] * imp[n0];
        const float s1 = a1 * invn[wv][n1 - kbeg] * imp[n1];
        const float s2 = a2 * invn[wv][n2 - kbeg] * imp[n2];
        const float s3 = a3 * invn[wv][n3 - kbeg] * imp[n3];
        topk_insert(tv, ti, s0, n0);
        if (n0 + 1 < kend) topk_insert(tv, ti, s1, n0 + 1);
        if (n0 + 2 < kend) topk_insert(tv, ti, s2, n0 + 2);
        if (n0 + 3 < kend) topk_insert(tv, ti, s3, n0 + 3);
    }

    // ---- per-block merge: 4 waves x 8 -> 8 per batch ----
#pragma unroll
    for (int j = 0; j < K; ++j) { mval[wv][lane][j] = tv[j]; midx[wv][lane][j] = ti[j]; }
    __syncthreads();
    if (wv == 0) {
        for (int r = 0; r < K; ++r) {
            float best = -INFINITY; int bw = 0, bj = 0;
            for (int w = 0; w < WPB; ++w)
#pragma unroll
                for (int j = 0; j < K; ++j) {
                    const float v = mval[w][lane][j];
                    if (v > best) { best = v; bw = w; bj = j; }
                }
            cval[((size_t)blockIdx.x * B + lane) * K + r] = best;
            cidx[((size_t)blockIdx.x * B + lane) * K + r] = midx[bw][lane][bj];
            mval[bw][lane][bj] = -INFINITY;
        }
    }
}

// ---------------------------------------------------------------------------
// Kernel 3: merge 512 blocks' candidates -> global top-8 per batch
__global__ __launch_bounds__(64)
void k3_merge(const float* __restrict__ cval, const int* __restrict__ cidx,
              int* __restrict__ topidx) {
    const int b    = blockIdx.x;
    const int lane = threadIdx.x;  // 0..63
    constexpr int NC = NBLK2 * K;  // 4096 candidates per batch

    __shared__ float sv[64 * (K + 1)];
    __shared__ int   si[64 * (K + 1)];

    float tv[K]; int ti[K];
#pragma unroll
    for (int j = 0; j < K; ++j) { tv[j] = -INFINITY; ti[j] = 0; }

    for (int i = 0; i < NC / 64; ++i) {
        const int e   = lane + 64 * i;
        const int blk = e >> 3, j = e & 7;
        const size_t a = ((size_t)blk * B + b) * K + j;
        const float v = cval[a];
        if (v > tv[K - 1]) topk_insert(tv, ti, v, cidx[a]);
    }
#pragma unroll
    for (int j = 0; j < K; ++j) {
        sv[lane * (K + 1) + j] = tv[j];
        si[lane * (K + 1) + j] = ti[j];
    }
    __syncthreads();

    for (int r = 0; r < K; ++r) {
        float best = -INFINITY; int bp = lane * (K + 1);
#pragma unroll
        for (int j = 0; j < K; ++j) {
            const float v = sv[lane * (K + 1) + j];
            if (v > best) { best = v; bp = lane * (K + 1) + j; }
        }
#pragma unroll
        for (int off = 32; off > 0; off >>= 1) {
            const float ov = __shfl_xor(best, off);
            const int   op = __shfl_xor(bp, off);
            if (ov > best || (ov == best && op < bp)) { best = ov; bp = op; }
        }
        if (lane == 0) {
            topidx[b * K + r] = si[bp];
            sv[bp] = -INFINITY;
        }
        __syncthreads();
    }
}

// ---------------------------------------------------------------------------
// Kernel 4: gather values, softmax attention, output projection
__global__ __launch_bounds__(128)
void k4_attend(const float* __restrict__ values, const int* __restrict__ topidx,
               const float* __restrict__ Wa, const float* __restrict__ ba,
               const float* __restrict__ Wc, const float* __restrict__ bc,
               float* __restrict__ out) {
    const int b = blockIdx.x;
    const int d = threadIdx.x;  // 0..127

    __shared__ float part[2][K];
    __shared__ float scores[K];
    __shared__ float comb[D];

    int idx[K];
#pragma unroll
    for (int k = 0; k < K; ++k) idx[k] = topidx[b * K + k];
    float v[K];
#pragma unroll
    for (int k = 0; k < K; ++k) v[k] = values[(size_t)idx[k] * D + d];

    const float wa = Wa[d];
    const int wvv = d >> 6;
#pragma unroll
    for (int k = 0; k < K; ++k) {
        float p = v[k] * wa;
#pragma unroll
        for (int off = 32; off > 0; off >>= 1) p += __shfl_xor(p, off);
        if ((d & 63) == 0) part[wvv][k] = p;
    }
    __syncthreads();
    if (d == 0) {
        float lg[K]; float mx = -INFINITY;
#pragma unroll
        for (int k = 0; k < K; ++k) { lg[k] = part[0][k] + part[1][k] + ba[0]; mx = fmaxf(mx, lg[k]); }
        float sum = 0.0f;
#pragma unroll
        for (int k = 0; k < K; ++k) { lg[k] = expf(lg[k] - mx); sum += lg[k]; }
        const float rs = 1.0f / sum;
#pragma unroll
        for (int k = 0; k < K; ++k) scores[k] = lg[k] * rs;
    }
    __syncthreads();

    float c = 0.0f;
#pragma unroll
    for (int k = 0; k < K; ++k) c = fmaf(scores[k], v[k], c);
    comb[d] = c;
    __syncthreads();

    float acc = bc[d];
    for (int dd = 0; dd < D; ++dd) acc = fmaf(comb[dd], Wc[(size_t)dd * D + d], acc);
    out[(size_t)b * D + d] = acc;
}

// ---------------------------------------------------------------------------
extern "C" void kernel_launch(void* const* d_in, const int* in_sizes, int n_in,
                              void* d_out, int out_size, void* d_ws, size_t ws_size,
                              hipStream_t stream) {
    const float* query = (const float*)d_in[0];   // [64,512]
    const float* keys  = (const float*)d_in[1];   // [200000,128]
    const float* vals  = (const float*)d_in[2];   // [200000,128]
    const float* imp   = (const float*)d_in[3];   // [200000]
    const float* Wq    = (const float*)d_in[4];   // [512,128]
    const float* bq    = (const float*)d_in[5];   // [128]
    const float* Wa    = (const float*)d_in[6];   // [128]
    const float* ba    = (const float*)d_in[7];   // [1]
    const float* Wc    = (const float*)d_in[8];   // [128,128]
    const float* bc    = (const float*)d_in[9];   // [128]
    // d_in[10] = top_k (always 8 per setup)

    float* out = (float*)d_out;

    // workspace layout (floats): ~2.1 MB
    float* qt     = (float*)d_ws;                 // 128*64
    float* cval   = qt + (size_t)D * B;           // 512*64*8
    int*   cidx   = (int*)(cval + (size_t)NBLK2 * B * K);
    int*   topidx = cidx + (size_t)NBLK2 * B * K; // 64*8

    k1_qproj<<<B, 256, 0, stream>>>(query, Wq, bq, qt);
    k2_sim_topk<<<NBLK2, 256, 0, stream>>>(keys, imp, qt, cval, cidx);
    k3_merge<<<B, 64, 0, stream>>>(cval, cidx, topidx);
    k4_attend<<<B, D, 0, stream>>>(vals, topidx, Wa, ba, Wc, bc, out);
}